// Round 5
// baseline (450.549 us; speedup 1.0000x reference)
//
#include <hip/hip_runtime.h>
#include <stdint.h>

// ---------------------------------------------------------------------------
// ThirdOrderAttention: B=1, N=256, C=512, H=8, D=64
// Flash attention over virtual L=65536 KV (K'=kj*kk, V'=vj*vk), bf16 MFMA.
// R5: vj factored out of PV (wave does its 2 j's sequentially, G-only
// accumulator, PV A-operand = pre-packed bf16 vk^T loads); per-block LDS
// Y-tile accumulated via shared-mem atomicAdd; launch_bounds(256,3) for
// 3 waves/SIMD (R4 was register-bound at 2).
// ---------------------------------------------------------------------------

typedef __attribute__((ext_vector_type(4))) float f32x4;
typedef __attribute__((ext_vector_type(4))) short s16x4;
typedef __attribute__((ext_vector_type(8))) short s16x8;

#define H_ 8
#define N_ 256
#define D_ 64
#define C_ 512
#define NC5 2560
#define SCALE_LOG2E 0.1803368801111204f  // 0.125 * log2(e): P = exp2(S')

// ----- bf16 helpers --------------------------------------------------------
__device__ __forceinline__ unsigned short f2bf_rne(float x) {
  union { float f; unsigned u; } a; a.f = x;
  unsigned r = a.u + 0x7fffu + ((a.u >> 16) & 1u);
  return (unsigned short)(r >> 16);
}

__device__ __forceinline__ unsigned pk_bf16(float a, float b) {
#if __has_builtin(__builtin_amdgcn_cvt_pk_bf16_f32)
  typedef __attribute__((ext_vector_type(2))) __bf16 bf16x2;
  union { bf16x2 v; unsigned u; } u;
  u.v = __builtin_amdgcn_cvt_pk_bf16_f32(a, b);
  return u.u;
#else
  return (unsigned)f2bf_rne(a) | ((unsigned)f2bf_rne(b) << 16);
#endif
}

// ----- MFMA wrappers -------------------------------------------------------
__device__ __forceinline__ f32x4 mfma32(s16x8 a, s16x8 b, f32x4 c) {
  return __builtin_amdgcn_mfma_f32_16x16x32_bf16(a, b, c, 0, 0, 0);
}

__device__ __forceinline__ f32x4 mfma16(s16x4 a, s16x4 b, f32x4 c) {
#if __has_builtin(__builtin_amdgcn_mfma_f32_16x16x16bf16_1k)
  return __builtin_amdgcn_mfma_f32_16x16x16bf16_1k(a, b, c, 0, 0, 0);
#else
  asm volatile("s_nop 1\n\t"
               "v_mfma_f32_16x16x16_bf16 %0, %1, %2, %0\n\t"
               "s_nop 7\n\t"
               "s_nop 2"
               : "+v"(c) : "v"(a), "v"(b));
  return c;
#endif
}

// ---------------------------------------------------------------------------
// Kernel 1: projection GEMM  p = x[256,512] @ W_att[512,2560] + b_att
// BM=16, BN=64, BK=32; 256 threads; 1x4 micro-tile. Grid (40, 16) = 640 blks.
// Epilogue: qS f32 (pre-scaled), kj f32, kk bf16, vj f32, vk^T bf16.
// ---------------------------------------------------------------------------
__global__ __launch_bounds__(256) void proj_kernel(
    const float* __restrict__ x, const float* __restrict__ W,
    const float* __restrict__ b,
    float* __restrict__ qS, float* __restrict__ kj,
    unsigned short* __restrict__ kkB, float* __restrict__ vj,
    unsigned short* __restrict__ vkBT) {
  __shared__ float As[32][17];
  __shared__ float Bs[32][68];
  const int bx = blockIdx.x;  // 40 col tiles of 64
  const int by = blockIdx.y;  // 16 row tiles of 16
  const int tid = threadIdx.x;
  const int m = tid >> 4;        // 0..15 output row
  const int c4 = (tid & 15) * 4; // output col group
  float acc0 = 0.f, acc1 = 0.f, acc2 = 0.f, acc3 = 0.f;

  const int lk = tid & 31;   // A-load k
  const int lm = tid >> 5;   // A-load m (0..7), +8 second half
  const int bk = tid >> 4;   // B-load k (0..15), +16 second half

  for (int k0 = 0; k0 < C_; k0 += 32) {
    As[lk][lm] = x[(by * 16 + lm) * C_ + k0 + lk];
    As[lk][lm + 8] = x[(by * 16 + lm + 8) * C_ + k0 + lk];
    *(f32x4*)&Bs[bk][c4] = *(const f32x4*)&W[(k0 + bk) * NC5 + bx * 64 + c4];
    *(f32x4*)&Bs[bk + 16][c4] =
        *(const f32x4*)&W[(k0 + bk + 16) * NC5 + bx * 64 + c4];
    __syncthreads();
#pragma unroll
    for (int kq = 0; kq < 32; ++kq) {
      float a = As[kq][m];
      f32x4 bv = *(const f32x4*)&Bs[kq][c4];
      acc0 += a * bv.x; acc1 += a * bv.y; acc2 += a * bv.z; acc3 += a * bv.w;
    }
    __syncthreads();
  }

  const int i = by * 16 + m;
  const int col0 = bx * 64 + c4;
  const int h = (bx * 64) / 320;
  const int part = ((bx * 64) % 320) >> 6;
  const int d0 = c4;
  float v0 = acc0 + b[col0 + 0];
  float v1 = acc1 + b[col0 + 1];
  float v2 = acc2 + b[col0 + 2];
  float v3 = acc3 + b[col0 + 3];
  const int idx = (h * N_ + i) * D_ + d0;
  if (part == 0) {
    f32x4 o = {v0 * SCALE_LOG2E, v1 * SCALE_LOG2E, v2 * SCALE_LOG2E,
               v3 * SCALE_LOG2E};
    *(f32x4*)(qS + idx) = o;
  } else if (part == 1) {
    f32x4 o = {v0, v1, v2, v3};
    *(f32x4*)(kj + idx) = o;
  } else if (part == 2) {
    union { unsigned u[2]; s16x4 v4; } t;
    t.u[0] = pk_bf16(v0, v1);
    t.u[1] = pk_bf16(v2, v3);
    *(s16x4*)(kkB + idx) = t.v4;
  } else if (part == 3) {
    f32x4 o = {v0, v1, v2, v3};
    *(f32x4*)(vj + idx) = o;
  } else {
    vkBT[(h * D_ + d0 + 0) * N_ + i] = f2bf_rne(v0);
    vkBT[(h * D_ + d0 + 1) * N_ + i] = f2bf_rne(v1);
    vkBT[(h * D_ + d0 + 2) * N_ + i] = f2bf_rne(v2);
    vkBT[(h * D_ + d0 + 3) * N_ + i] = f2bf_rne(v3);
  }
}

// ---------------------------------------------------------------------------
// Kernel 2: fused third-order flash attention.
// Grid (8 h, 4 ic of 64 i, 32 jc of 8 j). Block 256 = 4 waves; wave handles
// j = jc*8 + wave*2 + jj for jj in {0,1}, sequentially, 64 i, 256 k.
// Per j: q~ = bf16(qS*kj) fragments; per (k0, mb-slice of 16 t):
//   S^T = kk_bf16 . q~ (mfma 16x16x32); P = exp2(S');
//   S^T C-layout == mfma16 B-layout -> G^T[d,i] += vkB^T[d,t16] @ P^T.
// After each j: Y_lds[i,d] += vj[j,d]*G[i,d] via LDS atomicAdd (no barrier).
// Epilogue: single barrier, cooperative 16 KB slab write.
// ---------------------------------------------------------------------------
__global__ __launch_bounds__(256, 3) void flash3_kernel(
    const float* __restrict__ qS,            // [H][N][D] f32, pre-scaled
    const float* __restrict__ kjF,           // [H][N][D] f32
    const unsigned short* __restrict__ kkB,  // [H][N][D] bf16
    const float* __restrict__ vjF,           // [H][N][D] f32
    const unsigned short* __restrict__ vkBT, // [H][D][N] bf16
    float* __restrict__ slab,                // [H][32][4][64][64]
    float* __restrict__ lslab) {             // [H][32][256]
  __shared__ float Yl[64 * 68];  // 17.4 KB, stride 68 vs bank conflicts
  __shared__ float ll[64];

  const int h = blockIdx.x;
  const int ic = blockIdx.y;
  const int jc = blockIdx.z;
  const int wave = threadIdx.x >> 6;
  const int lane = threadIdx.x & 63;
  const int q = lane >> 4;
  const int c = lane & 15;
  const int i0 = ic * 64;

  for (int t = threadIdx.x; t < 64 * 68; t += 256) Yl[t] = 0.f;
  if (threadIdx.x < 64) ll[threadIdx.x] = 0.f;
  __syncthreads();

  const float* qh = qS + h * (N_ * D_);
  const float* kjh = kjF + h * (N_ * D_);
  const unsigned short* kkh = kkB + h * (N_ * D_);
  const float* vjh = vjF + h * (N_ * D_);
  const unsigned short* vkh = vkBT + h * (D_ * N_);

  float lac[4] = {0.f, 0.f, 0.f, 0.f};

  for (int jj = 0; jj < 2; ++jj) {
    const int j = jc * 8 + wave * 2 + jj;

    // q~ B-fragments for this j: B[k=d][n=i], q~ = bf16(qS * kj)
    const f32x4 kj0a = *(const f32x4*)(kjh + j * D_ + q * 8);
    const f32x4 kj0b = *(const f32x4*)(kjh + j * D_ + q * 8 + 4);
    const f32x4 kj1a = *(const f32x4*)(kjh + j * D_ + 32 + q * 8);
    const f32x4 kj1b = *(const f32x4*)(kjh + j * D_ + 32 + q * 8 + 4);
    s16x8 qf[4][2];
#pragma unroll
    for (int nb = 0; nb < 4; ++nb) {
      const float* qp = qh + (i0 + nb * 16 + c) * D_;
      f32x4 a0 = *(const f32x4*)(qp + q * 8);
      f32x4 a1 = *(const f32x4*)(qp + q * 8 + 4);
      f32x4 b0 = *(const f32x4*)(qp + 32 + q * 8);
      f32x4 b1 = *(const f32x4*)(qp + 32 + q * 8 + 4);
      union { unsigned u[4]; s16x8 v; } t0, t1;
      t0.u[0] = pk_bf16(a0.x * kj0a.x, a0.y * kj0a.y);
      t0.u[1] = pk_bf16(a0.z * kj0a.z, a0.w * kj0a.w);
      t0.u[2] = pk_bf16(a1.x * kj0b.x, a1.y * kj0b.y);
      t0.u[3] = pk_bf16(a1.z * kj0b.z, a1.w * kj0b.w);
      t1.u[0] = pk_bf16(b0.x * kj1a.x, b0.y * kj1a.y);
      t1.u[1] = pk_bf16(b0.z * kj1a.z, b0.w * kj1a.w);
      t1.u[2] = pk_bf16(b1.x * kj1b.x, b1.y * kj1b.y);
      t1.u[3] = pk_bf16(b1.z * kj1b.z, b1.w * kj1b.w);
      qf[nb][0] = t0.v;
      qf[nb][1] = t1.v;
    }

    f32x4 acc[4][4];  // G^T tiles: [md over d][nb over i]
#pragma unroll
    for (int md = 0; md < 4; ++md)
#pragma unroll
      for (int nb = 0; nb < 4; ++nb) acc[md][nb] = (f32x4){0.f, 0.f, 0.f, 0.f};

    for (int k0 = 0; k0 < N_; k0 += 64) {
#pragma unroll
      for (int mb = 0; mb < 4; ++mb) {
        // S A-frags: pre-cast bf16 kk rows (pure loads)
        const unsigned short* kp = kkh + (k0 + mb * 16 + c) * D_;
        s16x8 ka0 = *(const s16x8*)(kp + q * 8);
        s16x8 ka1 = *(const s16x8*)(kp + 32 + q * 8);
        // PV A-frags: pre-cast bf16 vk^T (pure 8B loads, no build)
        s16x4 av[4];
#pragma unroll
        for (int md = 0; md < 4; ++md)
          av[md] = *(const s16x4*)(vkh + (md * 16 + c) * N_ + k0 + mb * 16 +
                                   q * 4);

        f32x4 st[4];
#pragma unroll
        for (int nb = 0; nb < 4; ++nb) {
          f32x4 z = (f32x4){0.f, 0.f, 0.f, 0.f};
          z = mfma32(ka0, qf[nb][0], z);
          z = mfma32(ka1, qf[nb][1], z);
          st[nb] = z;
        }
        s16x4 pn[4];
#pragma unroll
        for (int nb = 0; nb < 4; ++nb) {
          float p0 = __builtin_exp2f(st[nb].x);
          float p1 = __builtin_exp2f(st[nb].y);
          float p2 = __builtin_exp2f(st[nb].z);
          float p3 = __builtin_exp2f(st[nb].w);
          lac[nb] += (p0 + p1) + (p2 + p3);
          union { unsigned u[2]; s16x4 v4; } t;
          t.u[0] = pk_bf16(p0, p1);
          t.u[1] = pk_bf16(p2, p3);
          pn[nb] = t.v4;
        }
#pragma unroll
        for (int md = 0; md < 4; ++md)
#pragma unroll
          for (int nb = 0; nb < 4; ++nb)
            acc[md][nb] = mfma16(av[md], pn[nb], acc[md][nb]);
      }
    }

    // Y_lds[i,d] += vj[j,d] * G[i,d]  (atomic; no inter-wave barrier needed)
#pragma unroll
    for (int md = 0; md < 4; ++md) {
      f32x4 vs = *(const f32x4*)(vjh + j * D_ + md * 16 + q * 4);
#pragma unroll
      for (int nb = 0; nb < 4; ++nb) {
        float* p = &Yl[(nb * 16 + c) * 68 + md * 16 + q * 4];
        atomicAdd(p + 0, acc[md][nb].x * vs.x);
        atomicAdd(p + 1, acc[md][nb].y * vs.y);
        atomicAdd(p + 2, acc[md][nb].z * vs.z);
        atomicAdd(p + 3, acc[md][nb].w * vs.w);
      }
    }
  }

  // l partials: quad-reduce then LDS atomic
#pragma unroll
  for (int nb = 0; nb < 4; ++nb) {
    float v = lac[nb];
    v += __shfl_xor(v, 16);
    v += __shfl_xor(v, 32);
    if (q == 0) atomicAdd(&ll[nb * 16 + c], v);
  }
  __syncthreads();

  // cooperative slab write: 64x64 f32 tile + 64 l values
  {
    float* out = slab + ((h * 32 + jc) * 4 + ic) * 4096;
    const int row = threadIdx.x >> 2;        // 0..63
    const int col0 = (threadIdx.x & 3) * 16; // 0,16,32,48
#pragma unroll
    for (int u = 0; u < 4; ++u)
      *(f32x4*)(out + row * 64 + col0 + u * 4) =
          *(const f32x4*)&Yl[row * 68 + col0 + u * 4];
    if (threadIdx.x < 64)
      lslab[(h * 32 + jc) * 256 + ic * 64 + threadIdx.x] = ll[threadIdx.x];
  }
}

// ---------------------------------------------------------------------------
// Kernel 3: reduce 32 j-chunk partials, normalize, head re-interleave.
// ---------------------------------------------------------------------------
__global__ __launch_bounds__(256) void reduce_kernel(
    const float* __restrict__ slab, const float* __restrict__ lslab,
    float* __restrict__ yn) {
  int idx = blockIdx.x * 256 + threadIdx.x;  // 131072 = 8h*4ic*64il*64d
  int h = idx >> 14;
  int r = idx & 16383;
  int ic = r >> 12;
  int il = (r >> 6) & 63;
  int d = r & 63;
  float s = 0.f, l = 0.f;
#pragma unroll 4
  for (int jc = 0; jc < 32; ++jc) {
    s += slab[(((h * 32 + jc) * 4 + ic) << 12) + il * 64 + d];
    l += lslab[(h * 32 + jc) * 256 + ic * 64 + il];
  }
  int i = ic * 64 + il;
  yn[i * C_ + h * 64 + d] = s / l;
}

// ---------------------------------------------------------------------------
// Kernel 4: out = yn[256,512] @ W_out[512,512] + b_out
// BM=16, BN=64, BK=32; grid (8,16) = 128 blocks.
// ---------------------------------------------------------------------------
__global__ __launch_bounds__(256) void out_gemm(
    const float* __restrict__ A, const float* __restrict__ W,
    const float* __restrict__ b, float* __restrict__ out) {
  __shared__ float As[32][17];
  __shared__ float Bs[32][68];
  const int bx = blockIdx.x;
  const int by = blockIdx.y;
  const int tid = threadIdx.x;
  const int m = tid >> 4;
  const int c4 = (tid & 15) * 4;
  float acc0 = 0.f, acc1 = 0.f, acc2 = 0.f, acc3 = 0.f;

  const int lk = tid & 31;
  const int lm = tid >> 5;
  const int bk = tid >> 4;

  for (int k0 = 0; k0 < C_; k0 += 32) {
    As[lk][lm] = A[(by * 16 + lm) * C_ + k0 + lk];
    As[lk][lm + 8] = A[(by * 16 + lm + 8) * C_ + k0 + lk];
    *(f32x4*)&Bs[bk][c4] = *(const f32x4*)&W[(k0 + bk) * C_ + bx * 64 + c4];
    *(f32x4*)&Bs[bk + 16][c4] =
        *(const f32x4*)&W[(k0 + bk + 16) * C_ + bx * 64 + c4];
    __syncthreads();
#pragma unroll
    for (int kq = 0; kq < 32; ++kq) {
      float a = As[kq][m];
      f32x4 bv = *(const f32x4*)&Bs[kq][c4];
      acc0 += a * bv.x; acc1 += a * bv.y; acc2 += a * bv.z; acc3 += a * bv.w;
    }
    __syncthreads();
  }

  const int i = by * 16 + m;
  const int col = bx * 64 + c4;
  f32x4 o = {acc0 + b[col + 0], acc1 + b[col + 1], acc2 + b[col + 2],
             acc3 + b[col + 3]};
  *(f32x4*)(out + i * C_ + col) = o;
}

// ---------------------------------------------------------------------------
extern "C" void kernel_launch(void* const* d_in, const int* in_sizes, int n_in,
                              void* d_out, int out_size, void* d_ws,
                              size_t ws_size, hipStream_t stream) {
  const float* x     = (const float*)d_in[0];
  const float* W_att = (const float*)d_in[1];
  const float* b_att = (const float*)d_in[2];
  const float* W_out = (const float*)d_in[3];
  const float* b_out = (const float*)d_in[4];

  char* ws = (char*)d_ws;
  float* slab           = (float*)(ws + 0);         // 16777216 B
  float* lslab          = (float*)(ws + 16777216);  //   262144 B
  float* qSb            = (float*)(ws + 17039360);  //   524288 B
  float* kj             = (float*)(ws + 17563648);  //   524288 B
  unsigned short* kkB   = (unsigned short*)(ws + 18087936);  // 262144 B
  float* vj             = (float*)(ws + 18350080);  //   524288 B
  unsigned short* vkBT  = (unsigned short*)(ws + 18874368);  // 262144 B
  float* yn             = (float*)(ws + 19398656);  //   524288 B

  proj_kernel<<<dim3(40, 16), 256, 0, stream>>>(x, W_att, b_att, qSb, kj, kkB,
                                                vj, vkBT);
  flash3_kernel<<<dim3(8, 4, 32), 256, 0, stream>>>(qSb, kj, kkB, vj, vkBT,
                                                    slab, lslab);
  reduce_kernel<<<dim3(512), 256, 0, stream>>>(slab, lslab, yn);
  out_gemm<<<dim3(8, 16), 256, 0, stream>>>(yn, W_out, b_out, (float*)d_out);
}

// Round 6
// 352.503 us; speedup vs baseline: 1.2781x; 1.2781x over previous
//
#include <hip/hip_runtime.h>
#include <stdint.h>

// ---------------------------------------------------------------------------
// ThirdOrderAttention: B=1, N=256, C=512, H=8, D=64
// Flash attention over virtual L=65536 KV (K'=kj*kk, V'=vj*vk), bf16 MFMA.
// R6: R5 algebra (vj factored, bf16 vk^T PV A-operands, LDS Y-tile) but with
// 32-i wave tiles (acc 32 regs, qf 16) so liveness ~120 fits the (256,3)
// budget (~168) with margin. R5 failed because nb=4 liveness ~156 + split
// allocation spilled. Grid (8h, 8ic, 16jc); wave = 4 j sequential.
// ---------------------------------------------------------------------------

typedef __attribute__((ext_vector_type(4))) float f32x4;
typedef __attribute__((ext_vector_type(4))) short s16x4;
typedef __attribute__((ext_vector_type(8))) short s16x8;

#define H_ 8
#define N_ 256
#define D_ 64
#define C_ 512
#define NC5 2560
#define SCALE_LOG2E 0.1803368801111204f  // 0.125 * log2(e): P = exp2(S')

// ----- bf16 helpers --------------------------------------------------------
__device__ __forceinline__ unsigned short f2bf_rne(float x) {
  union { float f; unsigned u; } a; a.f = x;
  unsigned r = a.u + 0x7fffu + ((a.u >> 16) & 1u);
  return (unsigned short)(r >> 16);
}

__device__ __forceinline__ unsigned pk_bf16(float a, float b) {
#if __has_builtin(__builtin_amdgcn_cvt_pk_bf16_f32)
  typedef __attribute__((ext_vector_type(2))) __bf16 bf16x2;
  union { bf16x2 v; unsigned u; } u;
  u.v = __builtin_amdgcn_cvt_pk_bf16_f32(a, b);
  return u.u;
#else
  return (unsigned)f2bf_rne(a) | ((unsigned)f2bf_rne(b) << 16);
#endif
}

// ----- MFMA wrappers -------------------------------------------------------
__device__ __forceinline__ f32x4 mfma32(s16x8 a, s16x8 b, f32x4 c) {
  return __builtin_amdgcn_mfma_f32_16x16x32_bf16(a, b, c, 0, 0, 0);
}

__device__ __forceinline__ f32x4 mfma16(s16x4 a, s16x4 b, f32x4 c) {
#if __has_builtin(__builtin_amdgcn_mfma_f32_16x16x16bf16_1k)
  return __builtin_amdgcn_mfma_f32_16x16x16bf16_1k(a, b, c, 0, 0, 0);
#else
  asm volatile("s_nop 1\n\t"
               "v_mfma_f32_16x16x16_bf16 %0, %1, %2, %0\n\t"
               "s_nop 7\n\t"
               "s_nop 2"
               : "+v"(c) : "v"(a), "v"(b));
  return c;
#endif
}

// ---------------------------------------------------------------------------
// Kernel 1: projection GEMM  p = x[256,512] @ W_att[512,2560] + b_att
// BM=16, BN=64, BK=32; 256 threads; 1x4 micro-tile. Grid (40, 16) = 640 blks.
// Epilogue: qS f32 (pre-scaled), kj f32, kk bf16, vj f32, vk^T bf16.
// ---------------------------------------------------------------------------
__global__ __launch_bounds__(256) void proj_kernel(
    const float* __restrict__ x, const float* __restrict__ W,
    const float* __restrict__ b,
    float* __restrict__ qS, float* __restrict__ kj,
    unsigned short* __restrict__ kkB, float* __restrict__ vj,
    unsigned short* __restrict__ vkBT) {
  __shared__ float As[32][17];
  __shared__ float Bs[32][68];
  const int bx = blockIdx.x;  // 40 col tiles of 64
  const int by = blockIdx.y;  // 16 row tiles of 16
  const int tid = threadIdx.x;
  const int m = tid >> 4;        // 0..15 output row
  const int c4 = (tid & 15) * 4; // output col group
  float acc0 = 0.f, acc1 = 0.f, acc2 = 0.f, acc3 = 0.f;

  const int lk = tid & 31;   // A-load k
  const int lm = tid >> 5;   // A-load m (0..7), +8 second half
  const int bk = tid >> 4;   // B-load k (0..15), +16 second half

  for (int k0 = 0; k0 < C_; k0 += 32) {
    As[lk][lm] = x[(by * 16 + lm) * C_ + k0 + lk];
    As[lk][lm + 8] = x[(by * 16 + lm + 8) * C_ + k0 + lk];
    *(f32x4*)&Bs[bk][c4] = *(const f32x4*)&W[(k0 + bk) * NC5 + bx * 64 + c4];
    *(f32x4*)&Bs[bk + 16][c4] =
        *(const f32x4*)&W[(k0 + bk + 16) * NC5 + bx * 64 + c4];
    __syncthreads();
#pragma unroll
    for (int kq = 0; kq < 32; ++kq) {
      float a = As[kq][m];
      f32x4 bv = *(const f32x4*)&Bs[kq][c4];
      acc0 += a * bv.x; acc1 += a * bv.y; acc2 += a * bv.z; acc3 += a * bv.w;
    }
    __syncthreads();
  }

  const int i = by * 16 + m;
  const int col0 = bx * 64 + c4;
  const int h = (bx * 64) / 320;
  const int part = ((bx * 64) % 320) >> 6;
  const int d0 = c4;
  float v0 = acc0 + b[col0 + 0];
  float v1 = acc1 + b[col0 + 1];
  float v2 = acc2 + b[col0 + 2];
  float v3 = acc3 + b[col0 + 3];
  const int idx = (h * N_ + i) * D_ + d0;
  if (part == 0) {
    f32x4 o = {v0 * SCALE_LOG2E, v1 * SCALE_LOG2E, v2 * SCALE_LOG2E,
               v3 * SCALE_LOG2E};
    *(f32x4*)(qS + idx) = o;
  } else if (part == 1) {
    f32x4 o = {v0, v1, v2, v3};
    *(f32x4*)(kj + idx) = o;
  } else if (part == 2) {
    union { unsigned u[2]; s16x4 v4; } t;
    t.u[0] = pk_bf16(v0, v1);
    t.u[1] = pk_bf16(v2, v3);
    *(s16x4*)(kkB + idx) = t.v4;
  } else if (part == 3) {
    f32x4 o = {v0, v1, v2, v3};
    *(f32x4*)(vj + idx) = o;
  } else {
    vkBT[(h * D_ + d0 + 0) * N_ + i] = f2bf_rne(v0);
    vkBT[(h * D_ + d0 + 1) * N_ + i] = f2bf_rne(v1);
    vkBT[(h * D_ + d0 + 2) * N_ + i] = f2bf_rne(v2);
    vkBT[(h * D_ + d0 + 3) * N_ + i] = f2bf_rne(v3);
  }
}

// ---------------------------------------------------------------------------
// Kernel 2: fused third-order flash attention.
// Grid (8 h, 8 ic of 32 i, 16 jc of 16 j). Block 256 = 4 waves; wave handles
// j = jc*16 + wave*4 + jj (jj<4) sequentially, 32 i, 256 k.
// Per j: q~ = bf16(qS*kj) B-frags (16 regs); per (k0, 16-t slice):
//   S^T = kk_bf16 . q~ (mfma32); P = exp2(S');
//   S^T C-layout == mfma16 B-layout -> G^T[d,i] += vkB^T[d,t16] @ P^T.
// After each j: Yl[i,d] += vj[j,d]*G[i,d] via LDS ds_add (no barrier).
// Epilogue: one barrier, cooperative 8 KB slab write.
// ---------------------------------------------------------------------------
__global__ __launch_bounds__(256, 3) void flash3_kernel(
    const float* __restrict__ qS,            // [H][N][D] f32, pre-scaled
    const float* __restrict__ kjF,           // [H][N][D] f32
    const unsigned short* __restrict__ kkB,  // [H][N][D] bf16
    const float* __restrict__ vjF,           // [H][N][D] f32
    const unsigned short* __restrict__ vkBT, // [H][D][N] bf16
    float* __restrict__ slab,                // [H][16][8][32][64]
    float* __restrict__ lslab) {             // [H][16][256]
  __shared__ float Yl[32 * 68];  // 8.7 KB, stride 68 vs bank conflicts
  __shared__ float ll[32];

  const int h = blockIdx.x;
  const int ic = blockIdx.y;  // 8 chunks of 32 i
  const int jc = blockIdx.z;  // 16 chunks of 16 j
  const int wave = threadIdx.x >> 6;
  const int lane = threadIdx.x & 63;
  const int q = lane >> 4;
  const int c = lane & 15;
  const int i0 = ic * 32;

  for (int t = threadIdx.x; t < 32 * 68; t += 256) Yl[t] = 0.f;
  if (threadIdx.x < 32) ll[threadIdx.x] = 0.f;
  __syncthreads();

  const float* qh = qS + h * (N_ * D_);
  const float* kjh = kjF + h * (N_ * D_);
  const unsigned short* kkh = kkB + h * (N_ * D_);
  const float* vjh = vjF + h * (N_ * D_);
  const unsigned short* vkh = vkBT + h * (D_ * N_);

  float lac[2] = {0.f, 0.f};

#pragma unroll 1
  for (int jj = 0; jj < 4; ++jj) {
    const int j = jc * 16 + wave * 4 + jj;

    // q~ B-fragments for this j: B[k=d][n=i], q~ = bf16(qS * kj)
    const f32x4 kj0a = *(const f32x4*)(kjh + j * D_ + q * 8);
    const f32x4 kj0b = *(const f32x4*)(kjh + j * D_ + q * 8 + 4);
    const f32x4 kj1a = *(const f32x4*)(kjh + j * D_ + 32 + q * 8);
    const f32x4 kj1b = *(const f32x4*)(kjh + j * D_ + 32 + q * 8 + 4);
    s16x8 qf[2][2];
#pragma unroll
    for (int nb = 0; nb < 2; ++nb) {
      const float* qp = qh + (i0 + nb * 16 + c) * D_;
      f32x4 a0 = *(const f32x4*)(qp + q * 8);
      f32x4 a1 = *(const f32x4*)(qp + q * 8 + 4);
      f32x4 b0 = *(const f32x4*)(qp + 32 + q * 8);
      f32x4 b1 = *(const f32x4*)(qp + 32 + q * 8 + 4);
      union { unsigned u[4]; s16x8 v; } t0, t1;
      t0.u[0] = pk_bf16(a0.x * kj0a.x, a0.y * kj0a.y);
      t0.u[1] = pk_bf16(a0.z * kj0a.z, a0.w * kj0a.w);
      t0.u[2] = pk_bf16(a1.x * kj0b.x, a1.y * kj0b.y);
      t0.u[3] = pk_bf16(a1.z * kj0b.z, a1.w * kj0b.w);
      t1.u[0] = pk_bf16(b0.x * kj1a.x, b0.y * kj1a.y);
      t1.u[1] = pk_bf16(b0.z * kj1a.z, b0.w * kj1a.w);
      t1.u[2] = pk_bf16(b1.x * kj1b.x, b1.y * kj1b.y);
      t1.u[3] = pk_bf16(b1.z * kj1b.z, b1.w * kj1b.w);
      qf[nb][0] = t0.v;
      qf[nb][1] = t1.v;
    }

    f32x4 acc[4][2];  // G^T tiles: [md over d][nb over i]
#pragma unroll
    for (int md = 0; md < 4; ++md)
#pragma unroll
      for (int nb = 0; nb < 2; ++nb) acc[md][nb] = (f32x4){0.f, 0.f, 0.f, 0.f};

#pragma unroll 1
    for (int k0 = 0; k0 < N_; k0 += 64) {
#pragma unroll
      for (int mb = 0; mb < 4; ++mb) {
        // S A-frags: pre-cast bf16 kk rows (pure loads)
        const unsigned short* kp = kkh + (k0 + mb * 16 + c) * D_;
        s16x8 ka0 = *(const s16x8*)(kp + q * 8);
        s16x8 ka1 = *(const s16x8*)(kp + 32 + q * 8);
        // PV A-frags: pre-cast bf16 vk^T (pure 8B loads)
        s16x4 av[4];
#pragma unroll
        for (int md = 0; md < 4; ++md)
          av[md] = *(const s16x4*)(vkh + (md * 16 + c) * N_ + k0 + mb * 16 +
                                   q * 4);

        f32x4 st[2];
#pragma unroll
        for (int nb = 0; nb < 2; ++nb) {
          f32x4 z = (f32x4){0.f, 0.f, 0.f, 0.f};
          z = mfma32(ka0, qf[nb][0], z);
          z = mfma32(ka1, qf[nb][1], z);
          st[nb] = z;
        }
        s16x4 pn[2];
#pragma unroll
        for (int nb = 0; nb < 2; ++nb) {
          float p0 = __builtin_exp2f(st[nb].x);
          float p1 = __builtin_exp2f(st[nb].y);
          float p2 = __builtin_exp2f(st[nb].z);
          float p3 = __builtin_exp2f(st[nb].w);
          lac[nb] += (p0 + p1) + (p2 + p3);
          union { unsigned u[2]; s16x4 v4; } t;
          t.u[0] = pk_bf16(p0, p1);
          t.u[1] = pk_bf16(p2, p3);
          pn[nb] = t.v4;
        }
#pragma unroll
        for (int md = 0; md < 4; ++md)
#pragma unroll
          for (int nb = 0; nb < 2; ++nb)
            acc[md][nb] = mfma16(av[md], pn[nb], acc[md][nb]);
      }
    }

    // Yl[i,d] += vj[j,d] * G[i,d]  (LDS atomic; no inter-wave barrier)
#pragma unroll
    for (int md = 0; md < 4; ++md) {
      f32x4 vs = *(const f32x4*)(vjh + j * D_ + md * 16 + q * 4);
#pragma unroll
      for (int nb = 0; nb < 2; ++nb) {
        float* p = &Yl[(nb * 16 + c) * 68 + md * 16 + q * 4];
        atomicAdd(p + 0, acc[md][nb].x * vs.x);
        atomicAdd(p + 1, acc[md][nb].y * vs.y);
        atomicAdd(p + 2, acc[md][nb].z * vs.z);
        atomicAdd(p + 3, acc[md][nb].w * vs.w);
      }
    }
  }

  // l partials: quad-reduce then LDS atomic
#pragma unroll
  for (int nb = 0; nb < 2; ++nb) {
    float v = lac[nb];
    v += __shfl_xor(v, 16);
    v += __shfl_xor(v, 32);
    if (q == 0) atomicAdd(&ll[nb * 16 + c], v);
  }
  __syncthreads();

  // cooperative slab write: 32x64 f32 tile + 32 l values
  {
    float* out = slab + ((h * 16 + jc) * 8 + ic) * 2048;
    const int row = threadIdx.x >> 3;        // 0..31
    const int col0 = (threadIdx.x & 7) * 8;  // 0..56
    *(f32x4*)(out + row * 64 + col0) = *(const f32x4*)&Yl[row * 68 + col0];
    *(f32x4*)(out + row * 64 + col0 + 4) =
        *(const f32x4*)&Yl[row * 68 + col0 + 4];
    if (threadIdx.x < 32)
      lslab[(h * 16 + jc) * 256 + ic * 32 + threadIdx.x] = ll[threadIdx.x];
  }
}

// ---------------------------------------------------------------------------
// Kernel 3: reduce 16 j-chunk partials, normalize, head re-interleave.
// ---------------------------------------------------------------------------
__global__ __launch_bounds__(256) void reduce_kernel(
    const float* __restrict__ slab, const float* __restrict__ lslab,
    float* __restrict__ yn) {
  int idx = blockIdx.x * 256 + threadIdx.x;  // 131072 = 8h*8ic*32il*64d
  int h = idx >> 14;
  int r = idx & 16383;
  int ic = r >> 11;
  int il = (r >> 6) & 31;
  int d = r & 63;
  float s = 0.f, l = 0.f;
#pragma unroll 4
  for (int jc = 0; jc < 16; ++jc) {
    s += slab[(((h * 16 + jc) * 8 + ic) << 11) + il * 64 + d];
    l += lslab[(h * 16 + jc) * 256 + ic * 32 + il];
  }
  int i = ic * 32 + il;
  yn[i * C_ + h * 64 + d] = s / l;
}

// ---------------------------------------------------------------------------
// Kernel 4: out = yn[256,512] @ W_out[512,512] + b_out
// BM=16, BN=64, BK=32; grid (8,16) = 128 blocks.
// ---------------------------------------------------------------------------
__global__ __launch_bounds__(256) void out_gemm(
    const float* __restrict__ A, const float* __restrict__ W,
    const float* __restrict__ b, float* __restrict__ out) {
  __shared__ float As[32][17];
  __shared__ float Bs[32][68];
  const int bx = blockIdx.x;
  const int by = blockIdx.y;
  const int tid = threadIdx.x;
  const int m = tid >> 4;
  const int c4 = (tid & 15) * 4;
  float acc0 = 0.f, acc1 = 0.f, acc2 = 0.f, acc3 = 0.f;

  const int lk = tid & 31;
  const int lm = tid >> 5;
  const int bk = tid >> 4;

  for (int k0 = 0; k0 < C_; k0 += 32) {
    As[lk][lm] = A[(by * 16 + lm) * C_ + k0 + lk];
    As[lk][lm + 8] = A[(by * 16 + lm + 8) * C_ + k0 + lk];
    *(f32x4*)&Bs[bk][c4] = *(const f32x4*)&W[(k0 + bk) * C_ + bx * 64 + c4];
    *(f32x4*)&Bs[bk + 16][c4] =
        *(const f32x4*)&W[(k0 + bk + 16) * C_ + bx * 64 + c4];
    __syncthreads();
#pragma unroll
    for (int kq = 0; kq < 32; ++kq) {
      float a = As[kq][m];
      f32x4 bv = *(const f32x4*)&Bs[kq][c4];
      acc0 += a * bv.x; acc1 += a * bv.y; acc2 += a * bv.z; acc3 += a * bv.w;
    }
    __syncthreads();
  }

  const int i = by * 16 + m;
  const int col = bx * 64 + c4;
  f32x4 o = {acc0 + b[col + 0], acc1 + b[col + 1], acc2 + b[col + 2],
             acc3 + b[col + 3]};
  *(f32x4*)(out + i * C_ + col) = o;
}

// ---------------------------------------------------------------------------
extern "C" void kernel_launch(void* const* d_in, const int* in_sizes, int n_in,
                              void* d_out, int out_size, void* d_ws,
                              size_t ws_size, hipStream_t stream) {
  const float* x     = (const float*)d_in[0];
  const float* W_att = (const float*)d_in[1];
  const float* b_att = (const float*)d_in[2];
  const float* W_out = (const float*)d_in[3];
  const float* b_out = (const float*)d_in[4];

  char* ws = (char*)d_ws;
  float* slab           = (float*)(ws + 0);         // 8388608 B
  float* lslab          = (float*)(ws + 8388608);   //  131072 B
  float* qSb            = (float*)(ws + 8519680);   //  524288 B
  float* kj             = (float*)(ws + 9043968);   //  524288 B
  unsigned short* kkB   = (unsigned short*)(ws + 9568256);   // 262144 B
  float* vj             = (float*)(ws + 9830400);   //  524288 B
  unsigned short* vkBT  = (unsigned short*)(ws + 10354688);  // 262144 B
  float* yn             = (float*)(ws + 10616832);  //  524288 B

  proj_kernel<<<dim3(40, 16), 256, 0, stream>>>(x, W_att, b_att, qSb, kj, kkB,
                                                vj, vkBT);
  flash3_kernel<<<dim3(8, 8, 16), 256, 0, stream>>>(qSb, kj, kkB, vj, vkBT,
                                                    slab, lslab);
  reduce_kernel<<<dim3(512), 256, 0, stream>>>(slab, lslab, yn);
  out_gemm<<<dim3(8, 16), 256, 0, stream>>>(yn, W_out, b_out, (float*)d_out);
}

// Round 7
// 351.736 us; speedup vs baseline: 1.2809x; 1.0022x over previous
//
#include <hip/hip_runtime.h>
#include <stdint.h>

// ---------------------------------------------------------------------------
// ThirdOrderAttention: B=1, N=256, C=512, H=8, D=64
// Flash attention over virtual L=65536 KV (K'=kj*kk, V'=vj*vk), bf16 MFMA.
// R7: R4 geometry (wave = 2j x 64i, (256,2)) + LDS double-buffered staging of
// kk/vk tiles via global_load_lds (16B), shared by all 4 waves. proj emits
// kk/vk in MFMA-fragment order so DMA(lane*16) == ds_read(lane*16) layout.
// Inner K-loop has zero global loads. R6 lesson: never trade compute density
// for occupancy in a latency-bound kernel.
// ---------------------------------------------------------------------------

typedef __attribute__((ext_vector_type(4))) float f32x4;
typedef __attribute__((ext_vector_type(4))) short s16x4;
typedef __attribute__((ext_vector_type(8))) short s16x8;

#define H_ 8
#define N_ 256
#define D_ 64
#define C_ 512
#define NC5 2560
#define SCALE_LOG2E 0.1803368801111204f  // 0.125 * log2(e): P = exp2(S')

// ----- bf16 helpers --------------------------------------------------------
__device__ __forceinline__ unsigned short f2bf_rne(float x) {
  union { float f; unsigned u; } a; a.f = x;
  unsigned r = a.u + 0x7fffu + ((a.u >> 16) & 1u);
  return (unsigned short)(r >> 16);
}

__device__ __forceinline__ unsigned pk_bf16(float a, float b) {
#if __has_builtin(__builtin_amdgcn_cvt_pk_bf16_f32)
  typedef __attribute__((ext_vector_type(2))) __bf16 bf16x2;
  union { bf16x2 v; unsigned u; } u;
  u.v = __builtin_amdgcn_cvt_pk_bf16_f32(a, b);
  return u.u;
#else
  return (unsigned)f2bf_rne(a) | ((unsigned)f2bf_rne(b) << 16);
#endif
}

// ----- MFMA wrappers -------------------------------------------------------
__device__ __forceinline__ f32x4 mfma32(s16x8 a, s16x8 b, f32x4 c) {
  return __builtin_amdgcn_mfma_f32_16x16x32_bf16(a, b, c, 0, 0, 0);
}

__device__ __forceinline__ f32x4 mfma16(s16x4 a, s16x4 b, f32x4 c) {
#if __has_builtin(__builtin_amdgcn_mfma_f32_16x16x16bf16_1k)
  return __builtin_amdgcn_mfma_f32_16x16x16bf16_1k(a, b, c, 0, 0, 0);
#else
  asm volatile("s_nop 1\n\t"
               "v_mfma_f32_16x16x16_bf16 %0, %1, %2, %0\n\t"
               "s_nop 7\n\t"
               "s_nop 2"
               : "+v"(c) : "v"(a), "v"(b));
  return c;
#endif
}

// ----- async global->LDS (16 B per lane; lds dest = base + lane*16) --------
__device__ __forceinline__ void dma16(const void* g, void* l) {
  __builtin_amdgcn_global_load_lds((const unsigned int*)g, (unsigned int*)l,
                                   16, 0, 0);
}

// ---------------------------------------------------------------------------
// Kernel 1: projection GEMM  p = x[256,512] @ W_att[512,2560] + b_att
// BM=16, BN=64, BK=32; grid (40,16)=640 blocks.
// Epilogue: qS f32 (pre-scaled), kj f32, vj f32,
//   kkF bf16 fragment-order  [h][kt][mb][half][lane=q*16+c][8]   (32 KB/h)
//   vkF bf16 fragment-order  [h][kt][mb][md][lane=q*16+c][4]     (32 KB/h)
// where t = kt*64+mb*16+{c | q*4+reg}, d = {half*32+q*8+idx | md*16+c}.
// ---------------------------------------------------------------------------
__global__ __launch_bounds__(256) void proj_kernel(
    const float* __restrict__ x, const float* __restrict__ W,
    const float* __restrict__ b,
    float* __restrict__ qS, float* __restrict__ kj,
    unsigned short* __restrict__ kkF, float* __restrict__ vj,
    unsigned short* __restrict__ vkF) {
  __shared__ float As[32][17];
  __shared__ float Bs[32][68];
  const int bx = blockIdx.x;  // 40 col tiles of 64
  const int by = blockIdx.y;  // 16 row tiles of 16
  const int tid = threadIdx.x;
  const int m = tid >> 4;        // 0..15 output row
  const int c4 = (tid & 15) * 4; // output col group
  float acc0 = 0.f, acc1 = 0.f, acc2 = 0.f, acc3 = 0.f;

  const int lk = tid & 31;
  const int lm = tid >> 5;
  const int bk = tid >> 4;

  for (int k0 = 0; k0 < C_; k0 += 32) {
    As[lk][lm] = x[(by * 16 + lm) * C_ + k0 + lk];
    As[lk][lm + 8] = x[(by * 16 + lm + 8) * C_ + k0 + lk];
    *(f32x4*)&Bs[bk][c4] = *(const f32x4*)&W[(k0 + bk) * NC5 + bx * 64 + c4];
    *(f32x4*)&Bs[bk + 16][c4] =
        *(const f32x4*)&W[(k0 + bk + 16) * NC5 + bx * 64 + c4];
    __syncthreads();
#pragma unroll
    for (int kq = 0; kq < 32; ++kq) {
      float a = As[kq][m];
      f32x4 bv = *(const f32x4*)&Bs[kq][c4];
      acc0 += a * bv.x; acc1 += a * bv.y; acc2 += a * bv.z; acc3 += a * bv.w;
    }
    __syncthreads();
  }

  const int i = by * 16 + m;  // token index
  const int col0 = bx * 64 + c4;
  const int h = (bx * 64) / 320;
  const int part = ((bx * 64) % 320) >> 6;
  const int d0 = c4;
  float v0 = acc0 + b[col0 + 0];
  float v1 = acc1 + b[col0 + 1];
  float v2 = acc2 + b[col0 + 2];
  float v3 = acc3 + b[col0 + 3];
  const int idx = (h * N_ + i) * D_ + d0;
  if (part == 0) {
    f32x4 o = {v0 * SCALE_LOG2E, v1 * SCALE_LOG2E, v2 * SCALE_LOG2E,
               v3 * SCALE_LOG2E};
    *(f32x4*)(qS + idx) = o;
  } else if (part == 1) {
    f32x4 o = {v0, v1, v2, v3};
    *(f32x4*)(kj + idx) = o;
  } else if (part == 2) {
    // kk fragment order: off = (((kt*4+mb)*2+half)*4+q)*128 + c*8 + idx0
    const int kt = i >> 6, mbt = (i >> 4) & 3, ct = i & 15;
    const int half = d0 >> 5, qd = (d0 >> 3) & 3, ix = d0 & 7;  // ix in {0,4}
    const int off =
        h * 16384 + (((kt * 4 + mbt) * 2 + half) * 4 + qd) * 128 + ct * 8 + ix;
    union { unsigned u[2]; s16x4 v4; } t;
    t.u[0] = pk_bf16(v0, v1);
    t.u[1] = pk_bf16(v2, v3);
    *(s16x4*)(kkF + off) = t.v4;
  } else if (part == 3) {
    f32x4 o = {v0, v1, v2, v3};
    *(f32x4*)(vj + idx) = o;
  } else {
    // vk fragment order: off = (((kt*4+mb)*4+md)*4+q)*64 + c*4 + reg
    const int kt = i >> 6, mbt = (i >> 4) & 3, qt = (i >> 2) & 3, rg = i & 3;
    const int md = d0 >> 4, cc = d0 & 15;
    const int base =
        h * 16384 + (((kt * 4 + mbt) * 4 + md) * 4 + qt) * 64 + rg;
    vkF[base + (cc + 0) * 4] = f2bf_rne(v0);
    vkF[base + (cc + 1) * 4] = f2bf_rne(v1);
    vkF[base + (cc + 2) * 4] = f2bf_rne(v2);
    vkF[base + (cc + 3) * 4] = f2bf_rne(v3);
  }
}

// ---------------------------------------------------------------------------
// Kernel 2: fused third-order flash attention, LDS-staged.
// Grid (8 h, 4 ic of 64 i, 32 jc of 8 j). Block 256 = 4 waves; wave owns 2 j
// (sequential), 64 i, 256 k. Flat loop it=0..7: jj=it>>2, kt=it&3.
//   prefetch tile kt+1 into buf^1 (global_load_lds x16, all waves share)
//   compute tile kt from buf: per 16-t slice: ds_read ka/av (contiguous),
//   S^T = ka . q~ (mfma32), P = exp2, G^T += av @ P^T (mfma16)
//   at jj end: Yl[i,d] += vj[j,d]*G[i,d] (LDS atomics); barrier.
// ---------------------------------------------------------------------------
__global__ __launch_bounds__(256, 2) void flash3_kernel(
    const float* __restrict__ qS,            // [H][N][D] f32, pre-scaled
    const float* __restrict__ kjF,           // [H][N][D] f32
    const unsigned short* __restrict__ kkF,  // fragment-ordered, 16384/h
    const float* __restrict__ vjF,           // [H][N][D] f32
    const unsigned short* __restrict__ vkF,  // fragment-ordered, 16384/h
    float* __restrict__ slab,                // [H][32][4][64][64]
    float* __restrict__ lslab) {             // [H][32][256]
  __shared__ __align__(16) short stage[2][8192];  // 2 x (8KB kk + 8KB vk)
  __shared__ float Yl[64 * 68];                   // 17.4 KB
  __shared__ float ll[64];

  const int h = blockIdx.x;
  const int ic = blockIdx.y;
  const int jc = blockIdx.z;
  const int wave = threadIdx.x >> 6;
  const int lane = threadIdx.x & 63;
  const int q = lane >> 4;
  const int c = lane & 15;
  const int i0 = ic * 64;

  for (int t = threadIdx.x; t < 64 * 68; t += 256) Yl[t] = 0.f;
  if (threadIdx.x < 64) ll[threadIdx.x] = 0.f;

  const float* qh = qS + h * (N_ * D_);
  const float* kjh = kjF + h * (N_ * D_);
  const float* vjh = vjF + h * (N_ * D_);
  const char* kkg = (const char*)(kkF + h * 16384);
  const char* vkg = (const char*)(vkF + h * 16384);
  const int n0 = wave * 2, n1 = wave * 2 + 1;  // this wave's DMA chunks

  // initial DMA: tile 0 -> buf 0
  {
    char* kd = (char*)&stage[0][0];
    char* vd = (char*)&stage[0][4096];
    dma16(kkg + n0 * 1024 + lane * 16, kd + n0 * 1024);
    dma16(kkg + n1 * 1024 + lane * 16, kd + n1 * 1024);
    dma16(vkg + n0 * 1024 + lane * 16, vd + n0 * 1024);
    dma16(vkg + n1 * 1024 + lane * 16, vd + n1 * 1024);
  }
  __syncthreads();

  float lac[4] = {0.f, 0.f, 0.f, 0.f};
  f32x4 acc[4][4];   // G^T tiles [md over d][nb over i]
  s16x8 qf[4][2];    // q~ B-fragments

#pragma unroll 1
  for (int it = 0; it < 8; ++it) {
    const int buf = it & 1;
    // prefetch next tile into the other buffer (overlaps compute below)
    if (it < 7) {
      const int nt = (it + 1) & 3;
      char* kd = (char*)&stage[buf ^ 1][0];
      char* vd = (char*)&stage[buf ^ 1][4096];
      dma16(kkg + nt * 8192 + n0 * 1024 + lane * 16, kd + n0 * 1024);
      dma16(kkg + nt * 8192 + n1 * 1024 + lane * 16, kd + n1 * 1024);
      dma16(vkg + nt * 8192 + n0 * 1024 + lane * 16, vd + n0 * 1024);
      dma16(vkg + nt * 8192 + n1 * 1024 + lane * 16, vd + n1 * 1024);
    }

    if ((it & 3) == 0) {  // start of a j: zero G, build q~ fragments
      const int j = jc * 8 + wave * 2 + (it >> 2);
#pragma unroll
      for (int md = 0; md < 4; ++md)
#pragma unroll
        for (int nb = 0; nb < 4; ++nb)
          acc[md][nb] = (f32x4){0.f, 0.f, 0.f, 0.f};
      const f32x4 kj0a = *(const f32x4*)(kjh + j * D_ + q * 8);
      const f32x4 kj0b = *(const f32x4*)(kjh + j * D_ + q * 8 + 4);
      const f32x4 kj1a = *(const f32x4*)(kjh + j * D_ + 32 + q * 8);
      const f32x4 kj1b = *(const f32x4*)(kjh + j * D_ + 32 + q * 8 + 4);
#pragma unroll
      for (int nb = 0; nb < 4; ++nb) {
        const float* qp = qh + (i0 + nb * 16 + c) * D_;
        f32x4 a0 = *(const f32x4*)(qp + q * 8);
        f32x4 a1 = *(const f32x4*)(qp + q * 8 + 4);
        f32x4 b0 = *(const f32x4*)(qp + 32 + q * 8);
        f32x4 b1 = *(const f32x4*)(qp + 32 + q * 8 + 4);
        union { unsigned u[4]; s16x8 v; } t0, t1;
        t0.u[0] = pk_bf16(a0.x * kj0a.x, a0.y * kj0a.y);
        t0.u[1] = pk_bf16(a0.z * kj0a.z, a0.w * kj0a.w);
        t0.u[2] = pk_bf16(a1.x * kj0b.x, a1.y * kj0b.y);
        t0.u[3] = pk_bf16(a1.z * kj0b.z, a1.w * kj0b.w);
        t1.u[0] = pk_bf16(b0.x * kj1a.x, b0.y * kj1a.y);
        t1.u[1] = pk_bf16(b0.z * kj1a.z, b0.w * kj1a.w);
        t1.u[2] = pk_bf16(b1.x * kj1b.x, b1.y * kj1b.y);
        t1.u[3] = pk_bf16(b1.z * kj1b.z, b1.w * kj1b.w);
        qf[nb][0] = t0.v;
        qf[nb][1] = t1.v;
      }
    }

    // compute on current buffer: 4 slices of 16 t
    const short* kkb = &stage[buf][0];
    const short* vkb = &stage[buf][4096];
#pragma unroll
    for (int mb = 0; mb < 4; ++mb) {
      s16x8 ka0 = *(const s16x8*)(kkb + mb * 1024 + lane * 8);
      s16x8 ka1 = *(const s16x8*)(kkb + mb * 1024 + 512 + lane * 8);
      s16x4 av[4];
#pragma unroll
      for (int md = 0; md < 4; ++md)
        av[md] = *(const s16x4*)(vkb + (mb * 4 + md) * 256 + lane * 4);

      f32x4 st[4];
#pragma unroll
      for (int nb = 0; nb < 4; ++nb) {
        f32x4 z = (f32x4){0.f, 0.f, 0.f, 0.f};
        z = mfma32(ka0, qf[nb][0], z);
        z = mfma32(ka1, qf[nb][1], z);
        st[nb] = z;
      }
      s16x4 pn[4];
#pragma unroll
      for (int nb = 0; nb < 4; ++nb) {
        float p0 = __builtin_exp2f(st[nb].x);
        float p1 = __builtin_exp2f(st[nb].y);
        float p2 = __builtin_exp2f(st[nb].z);
        float p3 = __builtin_exp2f(st[nb].w);
        lac[nb] += (p0 + p1) + (p2 + p3);
        union { unsigned u[2]; s16x4 v4; } t;
        t.u[0] = pk_bf16(p0, p1);
        t.u[1] = pk_bf16(p2, p3);
        pn[nb] = t.v4;
      }
#pragma unroll
      for (int md = 0; md < 4; ++md)
#pragma unroll
        for (int nb = 0; nb < 4; ++nb)
          acc[md][nb] = mfma16(av[md], pn[nb], acc[md][nb]);
    }

    if ((it & 3) == 3) {  // end of a j: Yl += vj * G (LDS atomics)
      const int j = jc * 8 + wave * 2 + (it >> 2);
#pragma unroll
      for (int md = 0; md < 4; ++md) {
        f32x4 vs = *(const f32x4*)(vjh + j * D_ + md * 16 + q * 4);
#pragma unroll
        for (int nb = 0; nb < 4; ++nb) {
          float* p = &Yl[(nb * 16 + c) * 68 + md * 16 + q * 4];
          atomicAdd(p + 0, acc[md][nb].x * vs.x);
          atomicAdd(p + 1, acc[md][nb].y * vs.y);
          atomicAdd(p + 2, acc[md][nb].z * vs.z);
          atomicAdd(p + 3, acc[md][nb].w * vs.w);
        }
      }
    }
    __syncthreads();  // drains prefetch DMA + guards buffer reuse
  }

  // l partials: quad-reduce then LDS atomic
#pragma unroll
  for (int nb = 0; nb < 4; ++nb) {
    float v = lac[nb];
    v += __shfl_xor(v, 16);
    v += __shfl_xor(v, 32);
    if (q == 0) atomicAdd(&ll[nb * 16 + c], v);
  }
  __syncthreads();

  // cooperative slab write: 64x64 f32 tile + 64 l values
  {
    float* out = slab + ((h * 32 + jc) * 4 + ic) * 4096;
    const int row = threadIdx.x >> 2;        // 0..63
    const int col0 = (threadIdx.x & 3) * 16; // 0,16,32,48
#pragma unroll
    for (int u = 0; u < 4; ++u)
      *(f32x4*)(out + row * 64 + col0 + u * 4) =
          *(const f32x4*)&Yl[row * 68 + col0 + u * 4];
    if (threadIdx.x < 64)
      lslab[(h * 32 + jc) * 256 + ic * 64 + threadIdx.x] = ll[threadIdx.x];
  }
}

// ---------------------------------------------------------------------------
// Kernel 3: reduce 32 j-chunk partials, normalize, head re-interleave.
// ---------------------------------------------------------------------------
__global__ __launch_bounds__(256) void reduce_kernel(
    const float* __restrict__ slab, const float* __restrict__ lslab,
    float* __restrict__ yn) {
  int idx = blockIdx.x * 256 + threadIdx.x;  // 131072 = 8h*4ic*64il*64d
  int h = idx >> 14;
  int r = idx & 16383;
  int ic = r >> 12;
  int il = (r >> 6) & 63;
  int d = r & 63;
  float s = 0.f, l = 0.f;
#pragma unroll 4
  for (int jc = 0; jc < 32; ++jc) {
    s += slab[(((h * 32 + jc) * 4 + ic) << 12) + il * 64 + d];
    l += lslab[(h * 32 + jc) * 256 + ic * 64 + il];
  }
  int i = ic * 64 + il;
  yn[i * C_ + h * 64 + d] = s / l;
}

// ---------------------------------------------------------------------------
// Kernel 4: out = yn[256,512] @ W_out[512,512] + b_out
// BM=16, BN=64, BK=32; grid (8,16) = 128 blocks.
// ---------------------------------------------------------------------------
__global__ __launch_bounds__(256) void out_gemm(
    const float* __restrict__ A, const float* __restrict__ W,
    const float* __restrict__ b, float* __restrict__ out) {
  __shared__ float As[32][17];
  __shared__ float Bs[32][68];
  const int bx = blockIdx.x;
  const int by = blockIdx.y;
  const int tid = threadIdx.x;
  const int m = tid >> 4;
  const int c4 = (tid & 15) * 4;
  float acc0 = 0.f, acc1 = 0.f, acc2 = 0.f, acc3 = 0.f;

  const int lk = tid & 31;
  const int lm = tid >> 5;
  const int bk = tid >> 4;

  for (int k0 = 0; k0 < C_; k0 += 32) {
    As[lk][lm] = A[(by * 16 + lm) * C_ + k0 + lk];
    As[lk][lm + 8] = A[(by * 16 + lm + 8) * C_ + k0 + lk];
    *(f32x4*)&Bs[bk][c4] = *(const f32x4*)&W[(k0 + bk) * C_ + bx * 64 + c4];
    *(f32x4*)&Bs[bk + 16][c4] =
        *(const f32x4*)&W[(k0 + bk + 16) * C_ + bx * 64 + c4];
    __syncthreads();
#pragma unroll
    for (int kq = 0; kq < 32; ++kq) {
      float a = As[kq][m];
      f32x4 bv = *(const f32x4*)&Bs[kq][c4];
      acc0 += a * bv.x; acc1 += a * bv.y; acc2 += a * bv.z; acc3 += a * bv.w;
    }
    __syncthreads();
  }

  const int i = by * 16 + m;
  const int col = bx * 64 + c4;
  f32x4 o = {acc0 + b[col + 0], acc1 + b[col + 1], acc2 + b[col + 2],
             acc3 + b[col + 3]};
  *(f32x4*)(out + i * C_ + col) = o;
}

// ---------------------------------------------------------------------------
extern "C" void kernel_launch(void* const* d_in, const int* in_sizes, int n_in,
                              void* d_out, int out_size, void* d_ws,
                              size_t ws_size, hipStream_t stream) {
  const float* x     = (const float*)d_in[0];
  const float* W_att = (const float*)d_in[1];
  const float* b_att = (const float*)d_in[2];
  const float* W_out = (const float*)d_in[3];
  const float* b_out = (const float*)d_in[4];

  char* ws = (char*)d_ws;
  float* slab           = (float*)(ws + 0);         // 16777216 B
  float* lslab          = (float*)(ws + 16777216);  //   262144 B
  float* qSb            = (float*)(ws + 17039360);  //   524288 B
  float* kj             = (float*)(ws + 17563648);  //   524288 B
  unsigned short* kkF   = (unsigned short*)(ws + 18087936);  // 262144 B
  float* vj             = (float*)(ws + 18350080);  //   524288 B
  unsigned short* vkF   = (unsigned short*)(ws + 18874368);  // 262144 B
  float* yn             = (float*)(ws + 19398656);  //   524288 B

  proj_kernel<<<dim3(40, 16), 256, 0, stream>>>(x, W_att, b_att, qSb, kj, kkF,
                                                vj, vkF);
  flash3_kernel<<<dim3(8, 4, 32), 256, 0, stream>>>(qSb, kj, kkF, vj, vkF,
                                                    slab, lslab);
  reduce_kernel<<<dim3(512), 256, 0, stream>>>(slab, lslab, yn);
  out_gemm<<<dim3(8, 16), 256, 0, stream>>>(yn, W_out, b_out, (float*)d_out);
}